// Round 1
// baseline (7103.086 us; speedup 1.0000x reference)
//
#include <hip/hip_runtime.h>

// ProjConvReducedI2T — fp32 correctness-first implementation (R1).
// Dims: BI=32 imgs, BT=128 caps, T=64, TXT=300, L=1024, R=128, G=2, KS=2.
// Pipeline: img stats -> img_vec -> cap_red (shared) -> hypernet kern gen+BN
//  -> [per image] conv(gen kern) -> BN stats -> c1 mix (+shared ax branch)
//  -> conv x2 (gen + static) -> BN stats -> c1 mix -> W_fc proj + max_t + l2norm + dot(iv).
// Images processed in 8 chunks of 4 (ws ~66MB).

#define EPSc 1e-5f

// ws offsets (in floats)
static const long OFF_IMG_GLOBAL = 0;        // 32*1024
static const long OFF_IV         = 32768;    // 32*1024
static const long OFF_IMG_VEC    = 65536;    // 32*128
static const long OFF_CAP_RED    = 69632;    // 128*128*64
static const long OFF_KERN       = 1118208;  // 2*32*16384
static const long OFF_GBIAS      = 2166784;  // 2*32*128
static const long OFF_AX0        = 2174976;  // 128*128*63
static const long OFF_SHARED1    = 3207168;  // 128*128*63
static const long OFF_ST_AX0     = 4239360;  // 256
static const long OFF_ST_PX0     = 4239616;  // 4*256
static const long OFF_ST_PX1     = 4240640;  // 4*256
static const long OFF_ST_AX1     = 4241664;  // 4*256
static const long OFF_P          = 4242688;  // 4*128*128*63
static const long OFF_E          = 8371456;  // 4*128*128*62
static const long OFF_Q          = 12434688; // 4*128*128*63

// ---- img_global (mean over 36 patches) + iv (l2norm) ----
__global__ void k_img(const float* __restrict__ img, float* __restrict__ img_global,
                      float* __restrict__ iv) {
  int b = blockIdx.x, tid = threadIdx.x;
  __shared__ float gl[1024];
  __shared__ float red[256];
  float ssq = 0.f;
  for (int l = tid; l < 1024; l += 256) {
    float s = 0.f;
    for (int p = 0; p < 36; ++p) s += img[((long)b*36 + p)*1024 + l];
    float g = s * (1.f/36.f);
    gl[l] = g;
    img_global[(long)b*1024 + l] = g;
    ssq += g*g;
  }
  red[tid] = ssq;
  __syncthreads();
  for (int off = 128; off > 0; off >>= 1) {
    if (tid < off) red[tid] += red[tid+off];
    __syncthreads();
  }
  float inv = rsqrtf(red[0]);
  for (int l = tid; l < 1024; l += 256) iv[(long)b*1024 + l] = gl[l]*inv;
}

// ---- img_vec = W_ri @ img_global + b_ri ----
__global__ void k_imgvec(const float* __restrict__ img_global, const float* __restrict__ W_ri,
                         const float* __restrict__ b_ri, float* __restrict__ img_vec) {
  int b = blockIdx.x, tid = threadIdx.x; // 128 threads
  __shared__ float gl[1024];
  for (int l = tid; l < 1024; l += 128) gl[l] = img_global[(long)b*1024 + l];
  __syncthreads();
  const float* w = W_ri + (long)tid*1024;
  float acc = b_ri[tid];
  for (int l = 0; l < 1024; l += 4) {
    float4 wv = *(const float4*)(w + l);
    float4 gv = *(const float4*)(gl + l);
    acc += wv.x*gv.x + wv.y*gv.y + wv.z*gv.z + wv.w*gv.w;
  }
  img_vec[(long)b*128 + tid] = acc;
}

// ---- cap_red[b][o][t] = W_rt @ cap_embed + b_rt ----
__global__ void k_capred(const float* __restrict__ cap, const float* __restrict__ W_rt,
                         const float* __restrict__ b_rt, float* __restrict__ cap_red) {
  int tg = blockIdx.x, b = blockIdx.y, tid = threadIdx.x; // 128 threads, tg<4 (16 t each)
  __shared__ float xs[300*16]; // [c][q]
  for (int idx = tid; idx < 16*300; idx += 128) {
    int q = idx / 300, c = idx - q*300;
    xs[c*16 + q] = cap[((long)b*64 + tg*16 + q)*300 + c];
  }
  __syncthreads();
  int o = tid;
  const float* w = W_rt + (long)o*300;
  float acc[16];
  float bb = b_rt[o];
  #pragma unroll
  for (int q = 0; q < 16; ++q) acc[q] = bb;
  for (int c = 0; c < 300; ++c) {
    float wv = w[c];
    const float* xp = &xs[c*16];
    float4 x0 = *(const float4*)(xp);
    float4 x1 = *(const float4*)(xp+4);
    float4 x2 = *(const float4*)(xp+8);
    float4 x3 = *(const float4*)(xp+12);
    acc[0]+=wv*x0.x; acc[1]+=wv*x0.y; acc[2]+=wv*x0.z; acc[3]+=wv*x0.w;
    acc[4]+=wv*x1.x; acc[5]+=wv*x1.y; acc[6]+=wv*x1.z; acc[7]+=wv*x1.w;
    acc[8]+=wv*x2.x; acc[9]+=wv*x2.y; acc[10]+=wv*x2.z; acc[11]+=wv*x2.w;
    acc[12]+=wv*x3.x; acc[13]+=wv*x3.y; acc[14]+=wv*x3.z; acc[15]+=wv*x3.w;
  }
  float* outp = cap_red + ((long)b*128 + o)*64 + tg*16;
  #pragma unroll
  for (int q = 0; q < 16; ++q) outp[q] = acc[q];
}

// ---- hypernet kernel gen: kern[j][i][k] = mk_W[j][k,:]@img_vec[i] + mk_b[j][k] ----
__global__ void k_kerngen(const float* __restrict__ mk_W, const float* __restrict__ mk_b,
                          const float* __restrict__ img_vec, float* __restrict__ kern) {
  int j = blockIdx.x >> 7, kb = blockIdx.x & 127, tid = threadIdx.x; // 128 threads
  int k = kb*128 + tid;
  __shared__ float bl[128*32]; // [r][i]
  for (int idx = tid; idx < 4096; idx += 128) {
    int i = idx >> 7, r = idx & 127;
    bl[r*32 + i] = img_vec[idx];
  }
  __syncthreads();
  const float* wrow = mk_W + ((long)j*16384 + k)*128;
  float acc[32];
  #pragma unroll
  for (int i = 0; i < 32; ++i) acc[i] = 0.f;
  for (int r = 0; r < 128; ++r) {
    float w = wrow[r];
    const float* bp = &bl[r*32];
    #pragma unroll
    for (int i = 0; i < 32; ++i) acc[i] += w * bp[i];
  }
  float kb_ = mk_b[(long)j*16384 + k];
  for (int i = 0; i < 32; ++i)
    kern[((long)j*32 + i)*16384 + k] = acc[i] + kb_;
}

// ---- BN over generated kernel rows (per o, 128 vals) + hypernet bias ----
__global__ void k_kernbn(float* __restrict__ kern, const float* __restrict__ wn_g,
                         const float* __restrict__ wn_b, const float* __restrict__ mbias_W,
                         const float* __restrict__ mbias_b, const float* __restrict__ img_vec,
                         float* __restrict__ gbias) {
  int j = blockIdx.x >> 5, i = blockIdx.x & 31, o = threadIdx.x; // 128 threads
  __shared__ float bs[128];
  bs[o] = img_vec[(long)i*128 + o];
  __syncthreads();
  float* row = kern + ((long)j*32 + i)*16384 + (long)o*128;
  float s = 0.f, q = 0.f;
  for (int c = 0; c < 128; ++c) { float v = row[c]; s += v; q += v*v; }
  float mean = s * (1.f/128.f);
  float var = q * (1.f/128.f) - mean*mean;
  float rstd = rsqrtf(var + EPSc);
  float sc = wn_g[j*128+o] * rstd;
  float sh = wn_b[j*128+o] - mean*sc;
  for (int c = 0; c < 128; ++c) row[c] = row[c]*sc + sh;
  float a = mbias_b[j*128+o];
  const float* mrow = mbias_W + ((long)j*128 + o)*128;
  for (int r = 0; r < 128; ++r) a += mrow[r]*bs[r];
  gbias[((long)j*32 + i)*128 + o] = a;
}

// ---- grouped conv1d KS=2 VALID: Y[ic][b][o][t] = bias + sum_{c',k} W[o][c'2+k]*X[ic][b][g64+c'][t+k]
__global__ void k_conv(const float* __restrict__ X, long xstr, int Tin, int Tout,
                       const float* __restrict__ Wt, long wstr,
                       const float* __restrict__ bias, int bstr,
                       float* __restrict__ Y, long ystr) {
  int b = blockIdx.x, ic = blockIdx.y, tid = threadIdx.x; // 256 threads
  __shared__ float xls[128*64];
  const float* Xb = X + (long)ic*xstr + (long)b*128*Tin;
  for (int idx = tid; idx < 128*Tin; idx += 256) {
    int c = idx / Tin, t = idx - c*Tin;
    xls[c*64 + t] = Xb[idx];
  }
  __syncthreads();
  int oi = tid & 63, tq = tid >> 6;
  int o0 = oi*2, g = o0 >> 6, t0 = tq*16;
  const float* wa = Wt + (long)ic*wstr + (long)o0*128;
  const float* wb = wa + 128;
  float acc0[16], acc1[16];
  #pragma unroll
  for (int tt = 0; tt < 16; ++tt) { acc0[tt] = 0.f; acc1[tt] = 0.f; }
  bool f16ok = (t0 + 16 < Tin);
  for (int cp = 0; cp < 64; ++cp) {
    float wa0 = wa[cp*2], wa1 = wa[cp*2+1];
    float wb0 = wb[cp*2], wb1 = wb[cp*2+1];
    const float* row = &xls[(g*64 + cp)*64 + t0];
    float f[17];
    float4 v0 = *(const float4*)(row);
    float4 v1 = *(const float4*)(row+4);
    float4 v2 = *(const float4*)(row+8);
    float4 v3 = *(const float4*)(row+12);
    f[0]=v0.x; f[1]=v0.y; f[2]=v0.z; f[3]=v0.w;
    f[4]=v1.x; f[5]=v1.y; f[6]=v1.z; f[7]=v1.w;
    f[8]=v2.x; f[9]=v2.y; f[10]=v2.z; f[11]=v2.w;
    f[12]=v3.x; f[13]=v3.y; f[14]=v3.z; f[15]=v3.w;
    f[16] = f16ok ? row[16] : 0.f;
    #pragma unroll
    for (int tt = 0; tt < 16; ++tt) {
      acc0[tt] += wa0*f[tt] + wa1*f[tt+1];
      acc1[tt] += wb0*f[tt] + wb1*f[tt+1];
    }
  }
  float bb0 = bias[ic*bstr + o0], bb1 = bias[ic*bstr + o0 + 1];
  float* y0 = Y + (long)ic*ystr + ((long)b*128 + o0)*Tout;
  float* y1 = y0 + Tout;
  #pragma unroll
  for (int tt = 0; tt < 16; ++tt) {
    int t = t0 + tt;
    if (t < Tout) { y0[t] = acc0[tt] + bb0; y1[t] = acc1[tt] + bb1; }
  }
}

// ---- per-channel BN stats over (BT, Tlen) -> scale/shift ----
__global__ void k_stats(const float* __restrict__ X, long xstr, int Tlen,
                        const float* __restrict__ gp, const float* __restrict__ bp,
                        float* __restrict__ st, int sstr) {
  int c = blockIdx.x, ic = blockIdx.y, tid = threadIdx.x; // 256 threads
  __shared__ float r1[256], r2[256];
  const float* base = X + (long)ic*xstr + (long)c*Tlen;
  int n = 128*Tlen;
  float s = 0.f, q = 0.f;
  for (int idx = tid; idx < n; idx += 256) {
    int b = idx / Tlen, t = idx - b*Tlen;
    float v = base[(long)b*128*Tlen + t];
    s += v; q += v*v;
  }
  r1[tid] = s; r2[tid] = q;
  __syncthreads();
  for (int off = 128; off > 0; off >>= 1) {
    if (tid < off) { r1[tid] += r1[tid+off]; r2[tid] += r2[tid+off]; }
    __syncthreads();
  }
  if (tid == 0) {
    float mean = r1[0] / n;
    float var = r2[0] / n - mean*mean;
    float rstd = rsqrtf(var + EPSc);
    float sc = gp[c]*rstd;
    st[(long)ic*sstr + c] = sc;
    st[(long)ic*sstr + 128 + c] = bp[c] - mean*sc;
  }
}

// ---- 1x1 channel-mix with fused BN+relu on input(s): Y = W * relu(bn(X1)) [+ W(:,128:)*relu(bn(X2))] + c1b [+ addbuf]
__global__ void k_mix(const float* __restrict__ X1, long x1s, const float* __restrict__ st1, int s1s,
                      const float* __restrict__ X2, long x2s, const float* __restrict__ st2, int s2s,
                      const float* __restrict__ W, int coloff1,
                      const float* __restrict__ c1b,
                      const float* __restrict__ addbuf,
                      float* __restrict__ Y, long ystr, int Tlen) {
  int b = blockIdx.x, ic = blockIdx.y, tid = threadIdx.x; // 256 threads
  __shared__ float xs[128*64];
  __shared__ float ssc[128], ssh[128];
  int o4 = (tid & 31)*4, tq = tid >> 5, t0 = tq*8;
  float acc[4][8];
  #pragma unroll
  for (int r = 0; r < 4; ++r) {
    float base0 = c1b ? c1b[o4+r] : 0.f;
    #pragma unroll
    for (int tt = 0; tt < 8; ++tt) {
      float v = base0;
      if (addbuf && (t0+tt) < Tlen) v += addbuf[((long)b*128 + o4 + r)*Tlen + t0 + tt];
      acc[r][tt] = v;
    }
  }
  // pass 1
  {
    const float* stp = st1 + (long)ic*s1s;
    if (tid < 128) { ssc[tid] = stp[tid]; ssh[tid] = stp[128+tid]; }
    __syncthreads();
    const float* Xb = X1 + (long)ic*x1s + (long)b*128*Tlen;
    for (int idx = tid; idx < 128*Tlen; idx += 256) {
      int c = idx / Tlen, t = idx - c*Tlen;
      xs[c*64 + t] = fmaxf(Xb[idx]*ssc[c] + ssh[c], 0.f);
    }
    __syncthreads();
    const float* Wb = W + coloff1;
    for (int c = 0; c < 128; ++c) {
      float4 f0 = *(const float4*)&xs[c*64 + t0];
      float4 f1 = *(const float4*)&xs[c*64 + t0 + 4];
      #pragma unroll
      for (int r = 0; r < 4; ++r) {
        float w = Wb[(long)(o4+r)*256 + c];
        acc[r][0] += w*f0.x; acc[r][1] += w*f0.y; acc[r][2] += w*f0.z; acc[r][3] += w*f0.w;
        acc[r][4] += w*f1.x; acc[r][5] += w*f1.y; acc[r][6] += w*f1.z; acc[r][7] += w*f1.w;
      }
    }
  }
  if (X2) {
    __syncthreads();
    const float* stp = st2 + (long)ic*s2s;
    if (tid < 128) { ssc[tid] = stp[tid]; ssh[tid] = stp[128+tid]; }
    __syncthreads();
    const float* Xb = X2 + (long)ic*x2s + (long)b*128*Tlen;
    for (int idx = tid; idx < 128*Tlen; idx += 256) {
      int c = idx / Tlen, t = idx - c*Tlen;
      xs[c*64 + t] = fmaxf(Xb[idx]*ssc[c] + ssh[c], 0.f);
    }
    __syncthreads();
    const float* Wb = W + 128;
    for (int c = 0; c < 128; ++c) {
      float4 f0 = *(const float4*)&xs[c*64 + t0];
      float4 f1 = *(const float4*)&xs[c*64 + t0 + 4];
      #pragma unroll
      for (int r = 0; r < 4; ++r) {
        float w = Wb[(long)(o4+r)*256 + c];
        acc[r][0] += w*f0.x; acc[r][1] += w*f0.y; acc[r][2] += w*f0.z; acc[r][3] += w*f0.w;
        acc[r][4] += w*f1.x; acc[r][5] += w*f1.y; acc[r][6] += w*f1.z; acc[r][7] += w*f1.w;
      }
    }
  }
  float* yb = Y + (long)ic*ystr + (long)b*128*Tlen;
  #pragma unroll
  for (int r = 0; r < 4; ++r) {
    #pragma unroll
    for (int tt = 0; tt < 8; ++tt) {
      int t = t0 + tt;
      if (t < Tlen) yb[(long)(o4+r)*Tlen + t] = acc[r][tt];
    }
  }
}

// ---- fc + max_t + l2norm + dot(iv) -> sims ----
__global__ void k_fc(const float* __restrict__ X, long xstr,
                     const float* __restrict__ Wfc, const float* __restrict__ bfc,
                     const float* __restrict__ ivp, float* __restrict__ outp) {
  int b = blockIdx.x, ic = blockIdx.y, tid = threadIdx.x; // 256 threads
  __shared__ float xls[128*64];
  __shared__ float r1[256], r2[256];
  const float* Xb = X + (long)ic*xstr + (long)b*128*62;
  for (int idx = tid; idx < 8192; idx += 256) {
    int c = idx >> 6, t = idx & 63;
    xls[idx] = (t < 62) ? Xb[(long)c*62 + t] : 0.f;
  }
  __syncthreads();
  int l0 = tid*4;
  float mx0 = -1e30f, mx1 = -1e30f, mx2 = -1e30f, mx3 = -1e30f;
  for (int tqi = 0; tqi < 4; ++tqi) {
    int t0 = tqi*16;
    float acc[4][16];
    #pragma unroll
    for (int r = 0; r < 4; ++r)
      #pragma unroll
      for (int tt = 0; tt < 16; ++tt) acc[r][tt] = 0.f;
    for (int c = 0; c < 128; ++c) {
      const float* row = &xls[c*64 + t0];
      float4 v0 = *(const float4*)(row);
      float4 v1 = *(const float4*)(row+4);
      float4 v2 = *(const float4*)(row+8);
      float4 v3 = *(const float4*)(row+12);
      float f[16];
      f[0]=v0.x; f[1]=v0.y; f[2]=v0.z; f[3]=v0.w;
      f[4]=v1.x; f[5]=v1.y; f[6]=v1.z; f[7]=v1.w;
      f[8]=v2.x; f[9]=v2.y; f[10]=v2.z; f[11]=v2.w;
      f[12]=v3.x; f[13]=v3.y; f[14]=v3.z; f[15]=v3.w;
      #pragma unroll
      for (int r = 0; r < 4; ++r) {
        float w = Wfc[(long)(l0+r)*128 + c];
        #pragma unroll
        for (int tt = 0; tt < 16; ++tt) acc[r][tt] += w*f[tt];
      }
    }
    int nt = 62 - t0; if (nt > 16) nt = 16;
    #pragma unroll
    for (int tt = 0; tt < 16; ++tt) {
      if (tt < nt) {
        mx0 = fmaxf(mx0, acc[0][tt]); mx1 = fmaxf(mx1, acc[1][tt]);
        mx2 = fmaxf(mx2, acc[2][tt]); mx3 = fmaxf(mx3, acc[3][tt]);
      }
    }
  }
  float ss = 0.f, dd = 0.f;
  {
    float tv;
    tv = mx0 + bfc[l0+0]; ss += tv*tv; dd += tv*ivp[(long)ic*1024 + l0+0];
    tv = mx1 + bfc[l0+1]; ss += tv*tv; dd += tv*ivp[(long)ic*1024 + l0+1];
    tv = mx2 + bfc[l0+2]; ss += tv*tv; dd += tv*ivp[(long)ic*1024 + l0+2];
    tv = mx3 + bfc[l0+3]; ss += tv*tv; dd += tv*ivp[(long)ic*1024 + l0+3];
  }
  r1[tid] = ss; r2[tid] = dd;
  __syncthreads();
  for (int off = 128; off > 0; off >>= 1) {
    if (tid < off) { r1[tid] += r1[tid+off]; r2[tid] += r2[tid+off]; }
    __syncthreads();
  }
  if (tid == 0) outp[ic*128 + b] = r2[0] * rsqrtf(r1[0]);
}

extern "C" void kernel_launch(void* const* d_in, const int* in_sizes, int n_in,
                              void* d_out, int out_size, void* d_ws, size_t ws_size,
                              hipStream_t stream) {
  (void)in_sizes; (void)n_in; (void)out_size; (void)ws_size;
  const float* img_embed = (const float*)d_in[0];
  const float* cap_embed = (const float*)d_in[1];
  const float* W_ri  = (const float*)d_in[2];
  const float* b_ri  = (const float*)d_in[3];
  const float* W_rt  = (const float*)d_in[4];
  const float* b_rt  = (const float*)d_in[5];
  const float* mk_W  = (const float*)d_in[6];
  const float* mk_b  = (const float*)d_in[7];
  const float* mbias_W = (const float*)d_in[8];
  const float* mbias_b = (const float*)d_in[9];
  const float* wn_g  = (const float*)d_in[10];
  const float* wn_b  = (const float*)d_in[11];
  const float* ca_W  = (const float*)d_in[12];
  const float* ca_b  = (const float*)d_in[13];
  const float* bn_g  = (const float*)d_in[14];
  const float* bn_b  = (const float*)d_in[15];
  const float* c1_W  = (const float*)d_in[16];
  const float* c1_b  = (const float*)d_in[17];
  const float* W_fc  = (const float*)d_in[18];
  const float* b_fc  = (const float*)d_in[19];
  float* out = (float*)d_out;
  float* ws  = (float*)d_ws;

  float* img_global = ws + OFF_IMG_GLOBAL;
  float* iv       = ws + OFF_IV;
  float* img_vec  = ws + OFF_IMG_VEC;
  float* cap_red  = ws + OFF_CAP_RED;
  float* kern     = ws + OFF_KERN;
  float* gbias    = ws + OFF_GBIAS;
  float* ax0      = ws + OFF_AX0;
  float* shared1  = ws + OFF_SHARED1;
  float* st_ax0   = ws + OFF_ST_AX0;
  float* st_px0   = ws + OFF_ST_PX0;
  float* st_px1   = ws + OFF_ST_PX1;
  float* st_ax1   = ws + OFF_ST_AX1;
  float* P        = ws + OFF_P;
  float* E        = ws + OFF_E;
  float* Q        = ws + OFF_Q;

  const long PS0 = 128L*128*63, PS1 = 128L*128*62;

  k_img<<<32, 256, 0, stream>>>(img_embed, img_global, iv);
  k_imgvec<<<32, 128, 0, stream>>>(img_global, W_ri, b_ri, img_vec);
  k_capred<<<dim3(4,128), 128, 0, stream>>>(cap_embed, W_rt, b_rt, cap_red);
  k_kerngen<<<256, 128, 0, stream>>>(mk_W, mk_b, img_vec, kern);
  k_kernbn<<<64, 128, 0, stream>>>(kern, wn_g, wn_b, mbias_W, mbias_b, img_vec, gbias);

  // shared layer-0 static branch: ax0 -> stats -> its half of the c1 mix
  k_conv<<<dim3(128,1), 256, 0, stream>>>(cap_red, 0, 64, 63, ca_W, 0, ca_b, 0, ax0, 0);
  k_stats<<<dim3(128,1), 256, 0, stream>>>(ax0, 0, 63, bn_g+128, bn_b+128, st_ax0, 0);
  k_mix<<<dim3(128,1), 256, 0, stream>>>(ax0, 0, st_ax0, 0, nullptr, 0, nullptr, 0,
                                         c1_W, 128, nullptr, nullptr, shared1, 0, 63);

  for (int ch = 0; ch < 8; ++ch) {
    int i0 = ch*4;
    // layer 0 (per-image half)
    k_conv<<<dim3(128,4), 256, 0, stream>>>(cap_red, 0, 64, 63, kern + (long)i0*16384, 16384,
                                            gbias + i0*128, 128, P, PS0);
    k_stats<<<dim3(128,4), 256, 0, stream>>>(P, PS0, 63, bn_g, bn_b, st_px0, 256);
    k_mix<<<dim3(128,4), 256, 0, stream>>>(P, PS0, st_px0, 256, nullptr, 0, nullptr, 0,
                                           c1_W, 0, c1_b, shared1, Q, PS0, 63);
    // layer 1
    k_conv<<<dim3(128,4), 256, 0, stream>>>(Q, PS0, 63, 62, kern + (32L + i0)*16384, 16384,
                                            gbias + (32 + i0)*128, 128, P, PS1);
    k_conv<<<dim3(128,4), 256, 0, stream>>>(Q, PS0, 63, 62, ca_W + 16384, 0, ca_b + 128, 0, E, PS1);
    k_stats<<<dim3(128,4), 256, 0, stream>>>(P, PS1, 62, bn_g + 256, bn_b + 256, st_px1, 256);
    k_stats<<<dim3(128,4), 256, 0, stream>>>(E, PS1, 62, bn_g + 256 + 128, bn_b + 256 + 128, st_ax1, 256);
    k_mix<<<dim3(128,4), 256, 0, stream>>>(P, PS1, st_px1, 256, E, PS1, st_ax1, 256,
                                           c1_W + 128*256, 0, c1_b + 128, nullptr, Q, PS1, 62);
    // fc + max_t + l2norm + dot(iv)
    k_fc<<<dim3(128,4), 256, 0, stream>>>(Q, PS1, W_fc, b_fc, iv + (long)i0*1024, out + i0*128);
  }
}

// Round 2
// 3455.402 us; speedup vs baseline: 2.0556x; 2.0556x over previous
//
#include <hip/hip_runtime.h>

// ProjConvReducedI2T — R2: fc stage moved to bf16 MFMA (fused max/l2norm/dot).
// Dims: BI=32 imgs, BT=128 caps, T=64, TXT=300, L=1024, R=128, G=2, KS=2.

#define EPSc 1e-5f

typedef __bf16 bf16x8 __attribute__((ext_vector_type(8)));
typedef float f32x4 __attribute__((ext_vector_type(4)));

// ws offsets (in floats)
static const long OFF_IMG_GLOBAL = 0;        // 32*1024
static const long OFF_IV         = 32768;    // 32*1024
static const long OFF_IMG_VEC    = 65536;    // 32*128
static const long OFF_CAP_RED    = 69632;    // 128*128*64
static const long OFF_KERN       = 1118208;  // 2*32*16384
static const long OFF_GBIAS      = 2166784;  // 2*32*128
static const long OFF_AX0        = 2174976;  // 128*128*63 (dead after prologue -> reused for Wfc_bf16)
static const long OFF_SHARED1    = 3207168;  // 128*128*63
static const long OFF_ST_AX0     = 4239360;  // 256
static const long OFF_ST_PX0     = 4239616;  // 4*256
static const long OFF_ST_PX1     = 4240640;  // 4*256
static const long OFF_ST_AX1     = 4241664;  // 4*256
static const long OFF_P          = 4242688;  // 4*128*128*63 (dead after mix -> reused for Qt bf16)
static const long OFF_E          = 8371456;  // 4*128*128*62
static const long OFF_Q          = 12434688; // 4*128*128*63

__device__ inline unsigned short f2bf(float f) {
  union { float f; unsigned u; } v; v.f = f;
  unsigned u = v.u;
  return (unsigned short)((u + 0x7FFFu + ((u >> 16) & 1u)) >> 16);
}

// ---- img_global (mean over 36 patches) + iv (l2norm) ----
__global__ void k_img(const float* __restrict__ img, float* __restrict__ img_global,
                      float* __restrict__ iv) {
  int b = blockIdx.x, tid = threadIdx.x;
  __shared__ float gl[1024];
  __shared__ float red[256];
  float ssq = 0.f;
  for (int l = tid; l < 1024; l += 256) {
    float s = 0.f;
    for (int p = 0; p < 36; ++p) s += img[((long)b*36 + p)*1024 + l];
    float g = s * (1.f/36.f);
    gl[l] = g;
    img_global[(long)b*1024 + l] = g;
    ssq += g*g;
  }
  red[tid] = ssq;
  __syncthreads();
  for (int off = 128; off > 0; off >>= 1) {
    if (tid < off) red[tid] += red[tid+off];
    __syncthreads();
  }
  float inv = rsqrtf(red[0]);
  for (int l = tid; l < 1024; l += 256) iv[(long)b*1024 + l] = gl[l]*inv;
}

// ---- img_vec = W_ri @ img_global + b_ri ----
__global__ void k_imgvec(const float* __restrict__ img_global, const float* __restrict__ W_ri,
                         const float* __restrict__ b_ri, float* __restrict__ img_vec) {
  int b = blockIdx.x, tid = threadIdx.x; // 128 threads
  __shared__ float gl[1024];
  for (int l = tid; l < 1024; l += 128) gl[l] = img_global[(long)b*1024 + l];
  __syncthreads();
  const float* w = W_ri + (long)tid*1024;
  float acc = b_ri[tid];
  for (int l = 0; l < 1024; l += 4) {
    float4 wv = *(const float4*)(w + l);
    float4 gv = *(const float4*)(gl + l);
    acc += wv.x*gv.x + wv.y*gv.y + wv.z*gv.z + wv.w*gv.w;
  }
  img_vec[(long)b*128 + tid] = acc;
}

// ---- cap_red[b][o][t] = W_rt @ cap_embed + b_rt ----
__global__ void k_capred(const float* __restrict__ cap, const float* __restrict__ W_rt,
                         const float* __restrict__ b_rt, float* __restrict__ cap_red) {
  int tg = blockIdx.x, b = blockIdx.y, tid = threadIdx.x; // 128 threads, tg<4 (16 t each)
  __shared__ float xs[300*16]; // [c][q]
  for (int idx = tid; idx < 16*300; idx += 128) {
    int q = idx / 300, c = idx - q*300;
    xs[c*16 + q] = cap[((long)b*64 + tg*16 + q)*300 + c];
  }
  __syncthreads();
  int o = tid;
  const float* w = W_rt + (long)o*300;
  float acc[16];
  float bb = b_rt[o];
  #pragma unroll
  for (int q = 0; q < 16; ++q) acc[q] = bb;
  for (int c = 0; c < 300; ++c) {
    float wv = w[c];
    const float* xp = &xs[c*16];
    float4 x0 = *(const float4*)(xp);
    float4 x1 = *(const float4*)(xp+4);
    float4 x2 = *(const float4*)(xp+8);
    float4 x3 = *(const float4*)(xp+12);
    acc[0]+=wv*x0.x; acc[1]+=wv*x0.y; acc[2]+=wv*x0.z; acc[3]+=wv*x0.w;
    acc[4]+=wv*x1.x; acc[5]+=wv*x1.y; acc[6]+=wv*x1.z; acc[7]+=wv*x1.w;
    acc[8]+=wv*x2.x; acc[9]+=wv*x2.y; acc[10]+=wv*x2.z; acc[11]+=wv*x2.w;
    acc[12]+=wv*x3.x; acc[13]+=wv*x3.y; acc[14]+=wv*x3.z; acc[15]+=wv*x3.w;
  }
  float* outp = cap_red + ((long)b*128 + o)*64 + tg*16;
  #pragma unroll
  for (int q = 0; q < 16; ++q) outp[q] = acc[q];
}

// ---- hypernet kernel gen: kern[j][i][k] = mk_W[j][k,:]@img_vec[i] + mk_b[j][k] ----
__global__ void k_kerngen(const float* __restrict__ mk_W, const float* __restrict__ mk_b,
                          const float* __restrict__ img_vec, float* __restrict__ kern) {
  int j = blockIdx.x >> 7, kb = blockIdx.x & 127, tid = threadIdx.x; // 128 threads
  int k = kb*128 + tid;
  __shared__ float bl[128*32]; // [r][i]
  for (int idx = tid; idx < 4096; idx += 128) {
    int i = idx >> 7, r = idx & 127;
    bl[r*32 + i] = img_vec[idx];
  }
  __syncthreads();
  const float* wrow = mk_W + ((long)j*16384 + k)*128;
  float acc[32];
  #pragma unroll
  for (int i = 0; i < 32; ++i) acc[i] = 0.f;
  for (int r = 0; r < 128; ++r) {
    float w = wrow[r];
    const float* bp = &bl[r*32];
    #pragma unroll
    for (int i = 0; i < 32; ++i) acc[i] += w * bp[i];
  }
  float kb_ = mk_b[(long)j*16384 + k];
  for (int i = 0; i < 32; ++i)
    kern[((long)j*32 + i)*16384 + k] = acc[i] + kb_;
}

// ---- BN over generated kernel rows (per o, 128 vals) + hypernet bias ----
__global__ void k_kernbn(float* __restrict__ kern, const float* __restrict__ wn_g,
                         const float* __restrict__ wn_b, const float* __restrict__ mbias_W,
                         const float* __restrict__ mbias_b, const float* __restrict__ img_vec,
                         float* __restrict__ gbias) {
  int j = blockIdx.x >> 5, i = blockIdx.x & 31, o = threadIdx.x; // 128 threads
  __shared__ float bs[128];
  bs[o] = img_vec[(long)i*128 + o];
  __syncthreads();
  float* row = kern + ((long)j*32 + i)*16384 + (long)o*128;
  float s = 0.f, q = 0.f;
  for (int c = 0; c < 128; ++c) { float v = row[c]; s += v; q += v*v; }
  float mean = s * (1.f/128.f);
  float var = q * (1.f/128.f) - mean*mean;
  float rstd = rsqrtf(var + EPSc);
  float sc = wn_g[j*128+o] * rstd;
  float sh = wn_b[j*128+o] - mean*sc;
  for (int c = 0; c < 128; ++c) row[c] = row[c]*sc + sh;
  float a = mbias_b[j*128+o];
  const float* mrow = mbias_W + ((long)j*128 + o)*128;
  for (int r = 0; r < 128; ++r) a += mrow[r]*bs[r];
  gbias[((long)j*32 + i)*128 + o] = a;
}

// ---- grouped conv1d KS=2 VALID ----
__global__ void k_conv(const float* __restrict__ X, long xstr, int Tin, int Tout,
                       const float* __restrict__ Wt, long wstr,
                       const float* __restrict__ bias, int bstr,
                       float* __restrict__ Y, long ystr) {
  int b = blockIdx.x, ic = blockIdx.y, tid = threadIdx.x; // 256 threads
  __shared__ float xls[128*64];
  const float* Xb = X + (long)ic*xstr + (long)b*128*Tin;
  for (int idx = tid; idx < 128*Tin; idx += 256) {
    int c = idx / Tin, t = idx - c*Tin;
    xls[c*64 + t] = Xb[idx];
  }
  __syncthreads();
  int oi = tid & 63, tq = tid >> 6;
  int o0 = oi*2, g = o0 >> 6, t0 = tq*16;
  const float* wa = Wt + (long)ic*wstr + (long)o0*128;
  const float* wb = wa + 128;
  float acc0[16], acc1[16];
  #pragma unroll
  for (int tt = 0; tt < 16; ++tt) { acc0[tt] = 0.f; acc1[tt] = 0.f; }
  bool f16ok = (t0 + 16 < Tin);
  for (int cp = 0; cp < 64; ++cp) {
    float wa0 = wa[cp*2], wa1 = wa[cp*2+1];
    float wb0 = wb[cp*2], wb1 = wb[cp*2+1];
    const float* row = &xls[(g*64 + cp)*64 + t0];
    float f[17];
    float4 v0 = *(const float4*)(row);
    float4 v1 = *(const float4*)(row+4);
    float4 v2 = *(const float4*)(row+8);
    float4 v3 = *(const float4*)(row+12);
    f[0]=v0.x; f[1]=v0.y; f[2]=v0.z; f[3]=v0.w;
    f[4]=v1.x; f[5]=v1.y; f[6]=v1.z; f[7]=v1.w;
    f[8]=v2.x; f[9]=v2.y; f[10]=v2.z; f[11]=v2.w;
    f[12]=v3.x; f[13]=v3.y; f[14]=v3.z; f[15]=v3.w;
    f[16] = f16ok ? row[16] : 0.f;
    #pragma unroll
    for (int tt = 0; tt < 16; ++tt) {
      acc0[tt] += wa0*f[tt] + wa1*f[tt+1];
      acc1[tt] += wb0*f[tt] + wb1*f[tt+1];
    }
  }
  float bb0 = bias[ic*bstr + o0], bb1 = bias[ic*bstr + o0 + 1];
  float* y0 = Y + (long)ic*ystr + ((long)b*128 + o0)*Tout;
  float* y1 = y0 + Tout;
  #pragma unroll
  for (int tt = 0; tt < 16; ++tt) {
    int t = t0 + tt;
    if (t < Tout) { y0[t] = acc0[tt] + bb0; y1[t] = acc1[tt] + bb1; }
  }
}

// ---- per-channel BN stats over (BT, Tlen) -> scale/shift ----
__global__ void k_stats(const float* __restrict__ X, long xstr, int Tlen,
                        const float* __restrict__ gp, const float* __restrict__ bp,
                        float* __restrict__ st, int sstr) {
  int c = blockIdx.x, ic = blockIdx.y, tid = threadIdx.x; // 256 threads
  __shared__ float r1[256], r2[256];
  const float* base = X + (long)ic*xstr + (long)c*Tlen;
  int n = 128*Tlen;
  float s = 0.f, q = 0.f;
  for (int idx = tid; idx < n; idx += 256) {
    int b = idx / Tlen, t = idx - b*Tlen;
    float v = base[(long)b*128*Tlen + t];
    s += v; q += v*v;
  }
  r1[tid] = s; r2[tid] = q;
  __syncthreads();
  for (int off = 128; off > 0; off >>= 1) {
    if (tid < off) { r1[tid] += r1[tid+off]; r2[tid] += r2[tid+off]; }
    __syncthreads();
  }
  if (tid == 0) {
    float mean = r1[0] / n;
    float var = r2[0] / n - mean*mean;
    float rstd = rsqrtf(var + EPSc);
    float sc = gp[c]*rstd;
    st[(long)ic*sstr + c] = sc;
    st[(long)ic*sstr + 128 + c] = bp[c] - mean*sc;
  }
}

// ---- 1x1 channel-mix with fused BN+relu ----
__global__ void k_mix(const float* __restrict__ X1, long x1s, const float* __restrict__ st1, int s1s,
                      const float* __restrict__ X2, long x2s, const float* __restrict__ st2, int s2s,
                      const float* __restrict__ W, int coloff1,
                      const float* __restrict__ c1b,
                      const float* __restrict__ addbuf,
                      float* __restrict__ Y, long ystr, int Tlen) {
  int b = blockIdx.x, ic = blockIdx.y, tid = threadIdx.x; // 256 threads
  __shared__ float xs[128*64];
  __shared__ float ssc[128], ssh[128];
  int o4 = (tid & 31)*4, tq = tid >> 5, t0 = tq*8;
  float acc[4][8];
  #pragma unroll
  for (int r = 0; r < 4; ++r) {
    float base0 = c1b ? c1b[o4+r] : 0.f;
    #pragma unroll
    for (int tt = 0; tt < 8; ++tt) {
      float v = base0;
      if (addbuf && (t0+tt) < Tlen) v += addbuf[((long)b*128 + o4 + r)*Tlen + t0 + tt];
      acc[r][tt] = v;
    }
  }
  {
    const float* stp = st1 + (long)ic*s1s;
    if (tid < 128) { ssc[tid] = stp[tid]; ssh[tid] = stp[128+tid]; }
    __syncthreads();
    const float* Xb = X1 + (long)ic*x1s + (long)b*128*Tlen;
    for (int idx = tid; idx < 128*Tlen; idx += 256) {
      int c = idx / Tlen, t = idx - c*Tlen;
      xs[c*64 + t] = fmaxf(Xb[idx]*ssc[c] + ssh[c], 0.f);
    }
    __syncthreads();
    const float* Wb = W + coloff1;
    for (int c = 0; c < 128; ++c) {
      float4 f0 = *(const float4*)&xs[c*64 + t0];
      float4 f1 = *(const float4*)&xs[c*64 + t0 + 4];
      #pragma unroll
      for (int r = 0; r < 4; ++r) {
        float w = Wb[(long)(o4+r)*256 + c];
        acc[r][0] += w*f0.x; acc[r][1] += w*f0.y; acc[r][2] += w*f0.z; acc[r][3] += w*f0.w;
        acc[r][4] += w*f1.x; acc[r][5] += w*f1.y; acc[r][6] += w*f1.z; acc[r][7] += w*f1.w;
      }
    }
  }
  if (X2) {
    __syncthreads();
    const float* stp = st2 + (long)ic*s2s;
    if (tid < 128) { ssc[tid] = stp[tid]; ssh[tid] = stp[128+tid]; }
    __syncthreads();
    const float* Xb = X2 + (long)ic*x2s + (long)b*128*Tlen;
    for (int idx = tid; idx < 128*Tlen; idx += 256) {
      int c = idx / Tlen, t = idx - c*Tlen;
      xs[c*64 + t] = fmaxf(Xb[idx]*ssc[c] + ssh[c], 0.f);
    }
    __syncthreads();
    const float* Wb = W + 128;
    for (int c = 0; c < 128; ++c) {
      float4 f0 = *(const float4*)&xs[c*64 + t0];
      float4 f1 = *(const float4*)&xs[c*64 + t0 + 4];
      #pragma unroll
      for (int r = 0; r < 4; ++r) {
        float w = Wb[(long)(o4+r)*256 + c];
        acc[r][0] += w*f0.x; acc[r][1] += w*f0.y; acc[r][2] += w*f0.z; acc[r][3] += w*f0.w;
        acc[r][4] += w*f1.x; acc[r][5] += w*f1.y; acc[r][6] += w*f1.z; acc[r][7] += w*f1.w;
      }
    }
  }
  float* yb = Y + (long)ic*ystr + (long)b*128*Tlen;
  #pragma unroll
  for (int r = 0; r < 4; ++r) {
    #pragma unroll
    for (int tt = 0; tt < 8; ++tt) {
      int t = t0 + tt;
      if (t < Tlen) yb[(long)(o4+r)*Tlen + t] = acc[r][tt];
    }
  }
}

// ---- W_fc (1024x128 f32) -> bf16 ----
__global__ void k_wfc2bf(const float* __restrict__ W, unsigned short* __restrict__ out) {
  int idx = (blockIdx.x*256 + threadIdx.x)*4;
  float4 v = *(const float4*)(W + idx);
  unsigned short o[4] = { f2bf(v.x), f2bf(v.y), f2bf(v.z), f2bf(v.w) };
  *(uint2*)(out + idx) = *(const uint2*)(o);
}

// ---- Q (f32 [ic][b][c][62]) -> Qt (bf16 [ic*128+b][t(64,padded)][c]) ----
__global__ void k_q2t(const float* __restrict__ Q, long qstr, unsigned short* __restrict__ Qt) {
  int b = blockIdx.x, ic = blockIdx.y, tid = threadIdx.x; // 256 threads
  __shared__ float xls[128*65];
  const float* Xb = Q + (long)ic*qstr + (long)b*128*62;
  for (int idx = tid; idx < 128*64; idx += 256) {
    int c = idx >> 6, t = idx & 63;
    xls[c*65 + t] = (t < 62) ? Xb[(long)c*62 + t] : 0.f;
  }
  __syncthreads();
  int t = tid >> 2, c0 = (tid & 3)*32;
  unsigned short* ob = Qt + (((long)(ic*128 + b))*64 + t)*128 + c0;
  unsigned int tmp[16];
  #pragma unroll
  for (int p = 0; p < 16; ++p) {
    unsigned int lo = f2bf(xls[(c0 + p*2)*65 + t]);
    unsigned int hi = f2bf(xls[(c0 + p*2 + 1)*65 + t]);
    tmp[p] = lo | (hi << 16);
  }
  ((uint4*)ob)[0] = *(const uint4*)(tmp);
  ((uint4*)ob)[1] = *(const uint4*)(tmp+4);
  ((uint4*)ob)[2] = *(const uint4*)(tmp+8);
  ((uint4*)ob)[3] = *(const uint4*)(tmp+12);
}

// ---- fc via MFMA: E = Wfc(1024x128) @ X(128x62); fused max_t + bias + l2norm + dot(iv) ----
__global__ __launch_bounds__(256) void k_fc_mfma(
    const unsigned short* __restrict__ Qt, const unsigned short* __restrict__ Wb,
    const float* __restrict__ bfc, const float* __restrict__ ivp,
    float* __restrict__ outp) {
  int b = blockIdx.x, ic = blockIdx.y;
  int tid = threadIdx.x;
  int w = tid >> 6, lane = tid & 63;
  int lane15 = lane & 15, lane4 = lane >> 4;
  const unsigned short* Qb = Qt + ((long)(ic*128 + b))*64*128;
  // B fragments: B[k=c][n=t], lane: n = lane15, k = ks*32 + lane4*8 + j
  bf16x8 bfrag[4][4];
  #pragma unroll
  for (int nt = 0; nt < 4; ++nt)
    #pragma unroll
    for (int ks = 0; ks < 4; ++ks)
      bfrag[nt][ks] = *(const bf16x8*)(Qb + (nt*16 + lane15)*128 + ks*32 + lane4*8);
  float ss = 0.f, dd = 0.f;
  const float* ivb = ivp + (long)ic*1024;
  for (int i = 0; i < 16; ++i) {
    int ltg = i*4 + w; // l-tile 0..63
    const unsigned short* Ab = Wb + (long)(ltg*16 + lane15)*128 + lane4*8;
    bf16x8 a0 = *(const bf16x8*)(Ab);
    bf16x8 a1 = *(const bf16x8*)(Ab + 32);
    bf16x8 a2 = *(const bf16x8*)(Ab + 64);
    bf16x8 a3 = *(const bf16x8*)(Ab + 96);
    f32x4 acc0 = {0.f,0.f,0.f,0.f}, acc1 = {0.f,0.f,0.f,0.f};
    f32x4 acc2 = {0.f,0.f,0.f,0.f}, acc3 = {0.f,0.f,0.f,0.f};
    acc0 = __builtin_amdgcn_mfma_f32_16x16x32_bf16(a0, bfrag[0][0], acc0, 0,0,0);
    acc0 = __builtin_amdgcn_mfma_f32_16x16x32_bf16(a1, bfrag[0][1], acc0, 0,0,0);
    acc0 = __builtin_amdgcn_mfma_f32_16x16x32_bf16(a2, bfrag[0][2], acc0, 0,0,0);
    acc0 = __builtin_amdgcn_mfma_f32_16x16x32_bf16(a3, bfrag[0][3], acc0, 0,0,0);
    acc1 = __builtin_amdgcn_mfma_f32_16x16x32_bf16(a0, bfrag[1][0], acc1, 0,0,0);
    acc1 = __builtin_amdgcn_mfma_f32_16x16x32_bf16(a1, bfrag[1][1], acc1, 0,0,0);
    acc1 = __builtin_amdgcn_mfma_f32_16x16x32_bf16(a2, bfrag[1][2], acc1, 0,0,0);
    acc1 = __builtin_amdgcn_mfma_f32_16x16x32_bf16(a3, bfrag[1][3], acc1, 0,0,0);
    acc2 = __builtin_amdgcn_mfma_f32_16x16x32_bf16(a0, bfrag[2][0], acc2, 0,0,0);
    acc2 = __builtin_amdgcn_mfma_f32_16x16x32_bf16(a1, bfrag[2][1], acc2, 0,0,0);
    acc2 = __builtin_amdgcn_mfma_f32_16x16x32_bf16(a2, bfrag[2][2], acc2, 0,0,0);
    acc2 = __builtin_amdgcn_mfma_f32_16x16x32_bf16(a3, bfrag[2][3], acc2, 0,0,0);
    acc3 = __builtin_amdgcn_mfma_f32_16x16x32_bf16(a0, bfrag[3][0], acc3, 0,0,0);
    acc3 = __builtin_amdgcn_mfma_f32_16x16x32_bf16(a1, bfrag[3][1], acc3, 0,0,0);
    acc3 = __builtin_amdgcn_mfma_f32_16x16x32_bf16(a2, bfrag[3][2], acc3, 0,0,0);
    acc3 = __builtin_amdgcn_mfma_f32_16x16x32_bf16(a3, bfrag[3][3], acc3, 0,0,0);
    // D layout: col(t) = nt*16 + lane15, row(l) = ltg*16 + lane4*4 + r
    #pragma unroll
    for (int r = 0; r < 4; ++r) {
      float m = fmaxf(fmaxf(acc0[r], acc1[r]), acc2[r]);
      if (lane15 < 14) m = fmaxf(m, acc3[r]);   // t=48+lane15 valid iff <62
      m = fmaxf(m, __shfl_xor(m, 1));
      m = fmaxf(m, __shfl_xor(m, 2));
      m = fmaxf(m, __shfl_xor(m, 4));
      m = fmaxf(m, __shfl_xor(m, 8));
      if (lane15 == 0) {
        int l = ltg*16 + lane4*4 + r;
        float tv = m + bfc[l];
        ss += tv*tv;
        dd += tv*ivb[l];
      }
    }
  }
  #pragma unroll
  for (int mk = 1; mk < 64; mk <<= 1) { ss += __shfl_xor(ss, mk); dd += __shfl_xor(dd, mk); }
  __shared__ float s1[4], s2[4];
  if (lane == 0) { s1[w] = ss; s2[w] = dd; }
  __syncthreads();
  if (tid == 0) {
    float S = s1[0]+s1[1]+s1[2]+s1[3];
    float D = s2[0]+s2[1]+s2[2]+s2[3];
    outp[ic*128 + b] = D * rsqrtf(S);
  }
}

extern "C" void kernel_launch(void* const* d_in, const int* in_sizes, int n_in,
                              void* d_out, int out_size, void* d_ws, size_t ws_size,
                              hipStream_t stream) {
  (void)in_sizes; (void)n_in; (void)out_size; (void)ws_size;
  const float* img_embed = (const float*)d_in[0];
  const float* cap_embed = (const float*)d_in[1];
  const float* W_ri  = (const float*)d_in[2];
  const float* b_ri  = (const float*)d_in[3];
  const float* W_rt  = (const float*)d_in[4];
  const float* b_rt  = (const float*)d_in[5];
  const float* mk_W  = (const float*)d_in[6];
  const float* mk_b  = (const float*)d_in[7];
  const float* mbias_W = (const float*)d_in[8];
  const float* mbias_b = (const float*)d_in[9];
  const float* wn_g  = (const float*)d_in[10];
  const float* wn_b  = (const float*)d_in[11];
  const float* ca_W  = (const float*)d_in[12];
  const float* ca_b  = (const float*)d_in[13];
  const float* bn_g  = (const float*)d_in[14];
  const float* bn_b  = (const float*)d_in[15];
  const float* c1_W  = (const float*)d_in[16];
  const float* c1_b  = (const float*)d_in[17];
  const float* W_fc  = (const float*)d_in[18];
  const float* b_fc  = (const float*)d_in[19];
  float* out = (float*)d_out;
  float* ws  = (float*)d_ws;

  float* img_global = ws + OFF_IMG_GLOBAL;
  float* iv       = ws + OFF_IV;
  float* img_vec  = ws + OFF_IMG_VEC;
  float* cap_red  = ws + OFF_CAP_RED;
  float* kern     = ws + OFF_KERN;
  float* gbias    = ws + OFF_GBIAS;
  float* ax0      = ws + OFF_AX0;
  float* shared1  = ws + OFF_SHARED1;
  float* st_ax0   = ws + OFF_ST_AX0;
  float* st_px0   = ws + OFF_ST_PX0;
  float* st_px1   = ws + OFF_ST_PX1;
  float* st_ax1   = ws + OFF_ST_AX1;
  float* P        = ws + OFF_P;
  float* E        = ws + OFF_E;
  float* Q        = ws + OFF_Q;
  unsigned short* wfcb = (unsigned short*)(ws + OFF_AX0); // reuse ax0 (dead after prologue)
  unsigned short* Qt   = (unsigned short*)(ws + OFF_P);   // reuse P (dead after layer-1 mix)

  const long PS0 = 128L*128*63, PS1 = 128L*128*62;

  k_img<<<32, 256, 0, stream>>>(img_embed, img_global, iv);
  k_imgvec<<<32, 128, 0, stream>>>(img_global, W_ri, b_ri, img_vec);
  k_capred<<<dim3(4,128), 128, 0, stream>>>(cap_embed, W_rt, b_rt, cap_red);
  k_kerngen<<<256, 128, 0, stream>>>(mk_W, mk_b, img_vec, kern);
  k_kernbn<<<64, 128, 0, stream>>>(kern, wn_g, wn_b, mbias_W, mbias_b, img_vec, gbias);

  // shared layer-0 static branch
  k_conv<<<dim3(128,1), 256, 0, stream>>>(cap_red, 0, 64, 63, ca_W, 0, ca_b, 0, ax0, 0);
  k_stats<<<dim3(128,1), 256, 0, stream>>>(ax0, 0, 63, bn_g+128, bn_b+128, st_ax0, 0);
  k_mix<<<dim3(128,1), 256, 0, stream>>>(ax0, 0, st_ax0, 0, nullptr, 0, nullptr, 0,
                                         c1_W, 128, nullptr, nullptr, shared1, 0, 63);
  // ax0 now dead -> convert W_fc into its slot
  k_wfc2bf<<<128, 256, 0, stream>>>(W_fc, wfcb);

  for (int ch = 0; ch < 8; ++ch) {
    int i0 = ch*4;
    // layer 0 (per-image half)
    k_conv<<<dim3(128,4), 256, 0, stream>>>(cap_red, 0, 64, 63, kern + (long)i0*16384, 16384,
                                            gbias + i0*128, 128, P, PS0);
    k_stats<<<dim3(128,4), 256, 0, stream>>>(P, PS0, 63, bn_g, bn_b, st_px0, 256);
    k_mix<<<dim3(128,4), 256, 0, stream>>>(P, PS0, st_px0, 256, nullptr, 0, nullptr, 0,
                                           c1_W, 0, c1_b, shared1, Q, PS0, 63);
    // layer 1
    k_conv<<<dim3(128,4), 256, 0, stream>>>(Q, PS0, 63, 62, kern + (32L + i0)*16384, 16384,
                                            gbias + (32 + i0)*128, 128, P, PS1);
    k_conv<<<dim3(128,4), 256, 0, stream>>>(Q, PS0, 63, 62, ca_W + 16384, 0, ca_b + 128, 0, E, PS1);
    k_stats<<<dim3(128,4), 256, 0, stream>>>(P, PS1, 62, bn_g + 256, bn_b + 256, st_px1, 256);
    k_stats<<<dim3(128,4), 256, 0, stream>>>(E, PS1, 62, bn_g + 256 + 128, bn_b + 256 + 128, st_ax1, 256);
    k_mix<<<dim3(128,4), 256, 0, stream>>>(P, PS1, st_px1, 256, E, PS1, st_ax1, 256,
                                           c1_W + 128*256, 0, c1_b + 128, nullptr, Q, PS1, 62);
    // fc: transpose+bf16 then MFMA with fused max/l2norm/dot
    k_q2t<<<dim3(128,4), 256, 0, stream>>>(Q, PS1, Qt);
    k_fc_mfma<<<dim3(128,4), 256, 0, stream>>>(Qt, wfcb, b_fc, iv + (long)i0*1024, out + i0*128);
  }
}